// Round 6
// baseline (96117.981 us; speedup 1.0000x reference)
//
#include <hip/hip_runtime.h>
#include <hip/hip_cooperative_groups.h>

namespace cg = cooperative_groups;

#define B_ 32
#define S_ 512
#define E_ 256
#define H_ 512
#define G_ 2048
#define K_ 7
#define PADA 34   // phase A transposed act row stride (even -> aligned float2)
#define PADB 513  // phase B row-major act stride
#define PADC 5    // phase C transposed act row stride (4 batches + 1)

__device__ __forceinline__ float sigm(float x) { return 1.f / (1.f + expf(-x)); }

__global__ __launch_bounds__(512, 2) void fused_all(
        const int* __restrict__ x, const int* __restrict__ taskp,
        const float* __restrict__ embed,
        const float* __restrict__ Wx_t, const float* __restrict__ Wh_t,
        const float* __restrict__ b_t,
        const float* __restrict__ Ws_p1, const float* __restrict__ Ws_p2,
        const float* __restrict__ Us_w,
        const float* __restrict__ Wx_c, const float* __restrict__ Wh_c,
        const float* __restrict__ Wm_c, const float* __restrict__ b_c,
        float* __restrict__ out,
        float* __restrict__ emb, float* __restrict__ p1t,
        float* __restrict__ h_task, float* __restrict__ c_task,
        float* __restrict__ h_main, float* __restrict__ c_main,
        float* __restrict__ p2w, float* __restrict__ partial)
{
    cg::grid_group grid = cg::this_grid();
    __shared__ float sact[512 * PADA];   // 69,632 B (A); B uses [32][513]; C uses [1280][5]
    __shared__ float swt[2][4096];       // 32,768 B weight double-buffer
    __shared__ float smisc[2048];        //  8,192 B gates / softmax scratch

    const int wg = blockIdx.x, tid = threadIdx.x;
    const int task = taskp[0];

    // ---------------- prologue: zero state, gather emb, transpose p1 ----------------
    for (int i = wg * 512 + tid; i < 393216; i += 131072)
        h_task[i] = 0.f;  // h_task(2) + c_task + h_main(2) + c_main contiguous
    for (int w = wg * 2 + (tid >> 8); w < S_ * B_; w += 512) {
        int ts = w >> 5, b = w & 31;
        int tok = x[b * S_ + ts];
        emb[(size_t)w * E_ + (tid & 255)] = embed[(size_t)tok * E_ + (tid & 255)];
    }
    for (int i = wg * 512 + tid; i < H_ * H_; i += 131072) {
        int j = i >> 9, ii = i & 511;
        p1t[i] = Ws_p1[ii * H_ + j];
    }
    grid.sync();

    for (int t = 0; t < S_; ++t) {
        const int old = t & 1, nw = old ^ 1;
        float* ht_old = h_task + (size_t)old * K_ * B_ * H_;
        float* ht_new = h_task + (size_t)nw * K_ * B_ * H_;
        float* hm_old = h_main + (size_t)old * B_ * H_;
        float* hm_new = h_main + (size_t)nw * B_ * H_;

        // ================= Phase A: task gates+cell (wg<224) + p2 (224..231) =================
        if (wg < 232) {
            const int cp = tid & 31, bq = tid >> 5;   // col pair / batch pair
            const int l0 = 2 * cp;
            const int rr = tid >> 4, cc4 = (tid & 15) << 2;
            const bool istask = wg < 224;
            int k = 0, nt = 0, pb = 0, kk = 0;
            const float* W0; const float* W1; int n0, n1; size_t ld;
            if (istask) {
                k = wg >> 5; nt = wg & 31;
                kk = k + (k >= task);
                int gcolL = ((cc4 >> 4) << 9) + nt * 16 + (cc4 & 15);
                W0 = Wx_t + (size_t)kk * E_ * G_ + gcolL;
                W1 = Wh_t + (size_t)kk * H_ * G_ + gcolL;
                n0 = 4; n1 = 8; ld = G_;
            } else {
                pb = wg - 224;
                int gcolL = pb * 64 + cc4;
                W0 = Ws_p2 + gcolL;                      // rows 0..511: hm_old
                W1 = Ws_p2 + (size_t)512 * H_ + gcolL;   // rows 512..767: emb
                n0 = 8; n1 = 4; ld = H_;
            }
            float a00 = 0.f, a01 = 0.f, a10 = 0.f, a11 = 0.f;
            float4 R0, R1;
            for (int part = 0; part < 2; ++part) {
                if (istask) {
                    if (part == 0) {
                        for (int idx = tid; idx < 256 * 32; idx += 512) {
                            int r = idx & 255, b = idx >> 8;
                            sact[r * PADA + b] = emb[((size_t)t * B_ + b) * E_ + r];
                        }
                    } else {
                        for (int idx = tid; idx < 512 * 32; idx += 512) {
                            int r = idx & 511, b = idx >> 9;
                            sact[r * PADA + b] = ht_old[((size_t)k * B_ + b) * H_ + r];
                        }
                    }
                } else {
                    if (part == 0) {
                        for (int idx = tid; idx < 512 * 32; idx += 512) {
                            int r = idx & 511, b = idx >> 9;
                            sact[r * PADA + b] = hm_old[(size_t)b * H_ + r];
                        }
                    } else {
                        for (int idx = tid; idx < 256 * 32; idx += 512) {
                            int r = idx & 255, b = idx >> 8;
                            sact[r * PADA + b] = emb[((size_t)t * B_ + b) * E_ + r];
                        }
                    }
                }
                const float* W = part ? W1 : W0;
                const int NC = part ? n1 : n0;
                R0 = *(const float4*)(W + (size_t)rr * ld);
                R1 = *(const float4*)(W + (size_t)(rr + 32) * ld);
                __syncthreads();
                *(float4*)(swt[0] + rr * 64 + cc4) = R0;
                *(float4*)(swt[0] + (rr + 32) * 64 + cc4) = R1;
                if (NC > 1) {
                    R0 = *(const float4*)(W + (size_t)(64 + rr) * ld);
                    R1 = *(const float4*)(W + (size_t)(64 + rr + 32) * ld);
                }
                __syncthreads();
                int cur = 0;
                for (int ch = 0; ch < NC; ++ch) {
                    const float* wb = swt[cur] + l0;
                    const float* ab = sact + (size_t)(ch << 6) * PADA + 2 * bq;
#pragma unroll 8
                    for (int r = 0; r < 64; ++r) {
                        float2 w = *(const float2*)(wb + r * 64);
                        float2 av = *(const float2*)(ab + r * PADA);
                        a00 = fmaf(w.x, av.x, a00); a10 = fmaf(w.y, av.x, a10);
                        a01 = fmaf(w.x, av.y, a01); a11 = fmaf(w.y, av.y, a11);
                    }
                    __syncthreads();
                    if (ch + 1 < NC) {
                        *(float4*)(swt[cur ^ 1] + rr * 64 + cc4) = R0;
                        *(float4*)(swt[cur ^ 1] + (rr + 32) * 64 + cc4) = R1;
                        if (ch + 2 < NC) {
                            R0 = *(const float4*)(W + (size_t)((ch + 2) * 64 + rr) * ld);
                            R1 = *(const float4*)(W + (size_t)((ch + 2) * 64 + rr + 32) * ld);
                        }
                        __syncthreads();
                        cur ^= 1;
                    }
                }
            }
            if (istask) {
                smisc[(2 * bq) * 64 + l0]         = a00;
                smisc[(2 * bq) * 64 + l0 + 1]     = a10;
                smisc[(2 * bq + 1) * 64 + l0]     = a01;
                smisc[(2 * bq + 1) * 64 + l0 + 1] = a11;
                __syncthreads();
                int b = tid >> 4, hc = tid & 15;
                const float* bb = b_t + kk * G_ + nt * 16 + hc;
                float gi = smisc[b * 64 + hc]      + bb[0];
                float gf = smisc[b * 64 + 16 + hc] + bb[512];
                float gg = smisc[b * 64 + 32 + hc] + bb[1024];
                float go = smisc[b * 64 + 48 + hc] + bb[1536];
                size_t cidx = ((size_t)k * B_ + b) * H_ + nt * 16 + hc;
                float cold = c_task[cidx];
                float cn = sigm(gf) * cold + sigm(gi) * tanhf(gg);
                float hn = sigm(go) * tanhf(cn);
                c_task[cidx] = cn;
                ht_new[cidx] = hn;
            } else {
                p2w[(size_t)(2 * bq) * H_ + pb * 64 + l0]         = a00;
                p2w[(size_t)(2 * bq) * H_ + pb * 64 + l0 + 1]     = a10;
                p2w[(size_t)(2 * bq + 1) * H_ + pb * 64 + l0]     = a01;
                p2w[(size_t)(2 * bq + 1) * H_ + pb * 64 + l0 + 1] = a11;
            }
        }
        grid.sync();

        // ================= Phase B: attention partials (wg<224) =================
        if (wg < 224) {
            const int kt = wg >> 5, it = wg & 31;
            const int ci = tid & 15, b = tid >> 4;   // i-col, batch
            for (int idx = tid; idx < 512 * 32 / 4; idx += 512) {
                int b2 = idx >> 7, j4 = (idx & 127) << 2;
                float4 v = *(const float4*)(ht_new + ((size_t)kt * B_ + b2) * H_ + j4);
                float* d = sact + b2 * PADB + j4;
                d[0] = v.x; d[1] = v.y; d[2] = v.z; d[3] = v.w;
            }
            const int rb = tid >> 3, cb = (tid & 7) << 1;
            const float* Wp = p1t + it * 16 + cb;
            float2 Rb = *(const float2*)(Wp + (size_t)rb * H_);
            __syncthreads();
            *(float2*)(swt[0] + rb * 16 + cb) = Rb;
            Rb = *(const float2*)(Wp + (size_t)(64 + rb) * H_);
            __syncthreads();
            float acc = 0.f;
            const float* hb = sact + b * PADB;
            int cur = 0;
            for (int ch = 0; ch < 8; ++ch) {
                const float* wb = swt[cur] + ci;
                const float* ab = hb + (ch << 6);
#pragma unroll 8
                for (int r = 0; r < 64; ++r)
                    acc = fmaf(wb[r * 16], ab[r], acc);
                __syncthreads();
                if (ch + 1 < 8) {
                    *(float2*)(swt[cur ^ 1] + rb * 16 + cb) = Rb;
                    if (ch + 2 < 8)
                        Rb = *(const float2*)(Wp + (size_t)((ch + 2) * 64 + rb) * H_);
                    __syncthreads();
                    cur ^= 1;
                }
            }
            int icol = it * 16 + ci;
            float s = tanhf(acc + p2w[(size_t)b * H_ + icol]) * Us_w[icol];
#pragma unroll
            for (int m = 1; m < 16; m <<= 1) s += __shfl_xor(s, m, 64);
            if (ci == 0) partial[((size_t)kt * 32 + it) * 32 + b] = s;
        }
        grid.sync();

        // ================= Phase C: softmax+Rt+main gates+cell (all 256 wg) =================
        {
            const int bt = wg >> 5, nt = wg & 31;   // 4 batches, 16 h-cols
            const int cp = tid & 31, bl = (tid >> 5) & 3, ds = tid >> 7;
            const int l0 = 2 * cp;
            const int rr = tid >> 4, cc4 = (tid & 15) << 2;
            const int gcolL = ((cc4 >> 4) << 9) + nt * 16 + (cc4 & 15);
            float* ssi = smisc;           // 28
            float* sa  = smisc + 32;      // 28
            float* sgt = smisc + 64;      // 4*256
            if (tid < 28) {
                int kq = tid >> 2, b2 = tid & 3;
                float ssum = 0.f;
                for (int itq = 0; itq < 32; ++itq)
                    ssum += partial[((size_t)kq * 32 + itq) * 32 + 4 * bt + b2];
                ssi[b2 * 7 + kq] = ssum;
            }
            __syncthreads();
            if (tid < 4) {
                float mx = -1e30f;
                for (int kq = 0; kq < 7; ++kq) mx = fmaxf(mx, ssi[tid * 7 + kq]);
                float den = 0.f, e[7];
                for (int kq = 0; kq < 7; ++kq) { e[kq] = expf(ssi[tid * 7 + kq] - mx); den += e[kq]; }
                float rd = 1.f / den;
                for (int kq = 0; kq < 7; ++kq) sa[tid * 7 + kq] = e[kq] * rd;
            }
            __syncthreads();
            for (int idx = tid; idx < 256 * 4; idx += 512) {
                int r = idx & 255, b2 = idx >> 8;
                sact[r * PADC + b2] = emb[((size_t)t * B_ + 4 * bt + b2) * E_ + r];
            }
            for (int idx = tid; idx < 512 * 4; idx += 512) {
                int r = idx & 511, b2 = idx >> 9;
                sact[(256 + r) * PADC + b2] = hm_old[(size_t)(4 * bt + b2) * H_ + r];
            }
            for (int idx = tid; idx < 512 * 4; idx += 512) {
                int r = idx & 511, b2 = idx >> 9;
                float v = 0.f;
#pragma unroll
                for (int kq = 0; kq < 7; ++kq)
                    v = fmaf(sa[b2 * 7 + kq], ht_new[((size_t)kq * B_ + 4 * bt + b2) * H_ + r], v);
                sact[(768 + r) * PADC + b2] = v;
            }
            float a0 = 0.f, a1 = 0.f;
            float4 R0, R1;
            auto wptr = [&](int ch) -> const float* {
                if (ch < 4)  return Wx_c + (size_t)(ch << 6) * G_ + gcolL;
                if (ch < 12) return Wh_c + (size_t)((ch - 4) << 6) * G_ + gcolL;
                return Wm_c + (size_t)((ch - 12) << 6) * G_ + gcolL;
            };
            const float* W = wptr(0);
            R0 = *(const float4*)(W + (size_t)rr * G_);
            R1 = *(const float4*)(W + (size_t)(rr + 32) * G_);
            __syncthreads();
            *(float4*)(swt[0] + rr * 64 + cc4) = R0;
            *(float4*)(swt[0] + (rr + 32) * 64 + cc4) = R1;
            W = wptr(1);
            R0 = *(const float4*)(W + (size_t)rr * G_);
            R1 = *(const float4*)(W + (size_t)(rr + 32) * G_);
            __syncthreads();
            int cur = 0;
            for (int ch = 0; ch < 20; ++ch) {
                const float* wb = swt[cur] + (ds << 4) * 64 + l0;
                const float* ab = sact + (size_t)((ch << 6) + (ds << 4)) * PADC + bl;
#pragma unroll 8
                for (int r = 0; r < 16; ++r) {
                    float2 w = *(const float2*)(wb + r * 64);
                    float av = ab[r * PADC];
                    a0 = fmaf(w.x, av, a0);
                    a1 = fmaf(w.y, av, a1);
                }
                __syncthreads();
                if (ch + 1 < 20) {
                    *(float4*)(swt[cur ^ 1] + rr * 64 + cc4) = R0;
                    *(float4*)(swt[cur ^ 1] + (rr + 32) * 64 + cc4) = R1;
                    if (ch + 2 < 20) {
                        W = wptr(ch + 2);
                        R0 = *(const float4*)(W + (size_t)rr * G_);
                        R1 = *(const float4*)(W + (size_t)(rr + 32) * G_);
                    }
                    __syncthreads();
                    cur ^= 1;
                }
            }
            sgt[ds * 256 + bl * 64 + l0]     = a0;
            sgt[ds * 256 + bl * 64 + l0 + 1] = a1;
            __syncthreads();
            if (tid < 64) {
                int b2 = tid >> 4, hc = tid & 15;
                int gb = 4 * bt + b2;
                float g4[4];
#pragma unroll
                for (int g = 0; g < 4; ++g) {
                    int colx = g * 16 + hc;
                    g4[g] = sgt[b2 * 64 + colx] + sgt[256 + b2 * 64 + colx]
                          + sgt[512 + b2 * 64 + colx] + sgt[768 + b2 * 64 + colx]
                          + b_c[g * 512 + nt * 16 + hc];
                }
                size_t cidx = (size_t)gb * H_ + nt * 16 + hc;
                float cold = c_main[cidx];
                float cn = sigm(g4[1]) * cold + sigm(g4[0]) * tanhf(g4[2]);
                float hn = sigm(g4[3]) * tanhf(cn);
                c_main[cidx] = cn;
                hm_new[cidx] = hn;
                out[(size_t)gb * S_ * H_ + (size_t)t * H_ + nt * 16 + hc] = hn;
            }
        }
        grid.sync();
    }

    // final hN (after 512 steps, live buffer is h_main[0])
    for (int i = wg * 512 + tid; i < B_ * H_; i += 131072)
        out[(size_t)B_ * S_ * H_ + i] = h_main[i];
}

extern "C" void kernel_launch(void* const* d_in, const int* in_sizes, int n_in,
                              void* d_out, int out_size, void* d_ws, size_t ws_size,
                              hipStream_t stream) {
    const int*   x      = (const int*)d_in[0];
    const int*   taskp  = (const int*)d_in[1];
    const float* embed  = (const float*)d_in[2];
    const float* Wx_t   = (const float*)d_in[3];
    const float* Wh_t   = (const float*)d_in[4];
    const float* b_t    = (const float*)d_in[5];
    const float* Ws_p1  = (const float*)d_in[6];
    const float* Ws_p2  = (const float*)d_in[7];
    const float* Us_w   = (const float*)d_in[8];
    const float* Wx_c   = (const float*)d_in[10];
    const float* Wh_c   = (const float*)d_in[11];
    const float* Wm_c   = (const float*)d_in[12];
    const float* b_c    = (const float*)d_in[13];
    float* out = (float*)d_out;

    float* ws = (float*)d_ws;
    float* emb     = ws;                                  // S*B*E   = 4,194,304
    float* p1t     = emb     + (size_t)S_ * B_ * E_;      // H*H     =   262,144
    float* h_task  = p1t     + (size_t)H_ * H_;           // 2*K*B*H =   229,376
    float* c_task  = h_task  + 2 * (size_t)K_ * B_ * H_;  // K*B*H   =   114,688
    float* h_main  = c_task  + (size_t)K_ * B_ * H_;      // 2*B*H   =    32,768
    float* c_main  = h_main  + 2 * (size_t)B_ * H_;       // B*H     =    16,384
    float* p2      = c_main  + (size_t)B_ * H_;           // B*H     =    16,384
    float* partial = p2      + (size_t)B_ * H_;           // K*32*32 =     7,168

    void* args[] = { (void*)&x, (void*)&taskp, (void*)&embed,
                     (void*)&Wx_t, (void*)&Wh_t, (void*)&b_t,
                     (void*)&Ws_p1, (void*)&Ws_p2, (void*)&Us_w,
                     (void*)&Wx_c, (void*)&Wh_c, (void*)&Wm_c, (void*)&b_c,
                     (void*)&out,
                     (void*)&emb, (void*)&p1t, (void*)&h_task, (void*)&c_task,
                     (void*)&h_main, (void*)&c_main, (void*)&p2, (void*)&partial };
    hipLaunchCooperativeKernel((void*)fused_all, dim3(256), dim3(512), args, 0, stream);
}

// Round 8
// 67008.606 us; speedup vs baseline: 1.4344x; 1.4344x over previous
//
#include <hip/hip_runtime.h>

#define B_ 32
#define S_ 512
#define E_ 256
#define H_ 512
#define G_ 2048
#define K_ 7
#define PADA 34   // phase A transposed act row stride
#define PADB 513  // phase B row-major act stride
#define PADC 5    // phase C transposed act row stride

#define SCOPE_AGENT __HIP_MEMORY_SCOPE_AGENT

__device__ __forceinline__ float sigm(float x) { return 1.f / (1.f + expf(-x)); }

// agent-scope (cross-XCD-coherent) store: value lands at the coherent point.
__device__ __forceinline__ void stg(float* p, float v) {
    __hip_atomic_store(p, v, __ATOMIC_RELAXED, SCOPE_AGENT);
}

// Lightweight grid barrier: one fetch_add + relaxed spin per WG leader.
__device__ __forceinline__ void gbar(unsigned* bar, int tid, int nwg) {
    __syncthreads();
    if (tid == 0) {
        unsigned* cnt = bar;
        unsigned* gen = bar + 32;  // 128 B apart
        unsigned g = __hip_atomic_load(gen, __ATOMIC_RELAXED, SCOPE_AGENT);
        unsigned old = __hip_atomic_fetch_add(cnt, 1u, __ATOMIC_ACQ_REL, SCOPE_AGENT);
        if (old == (unsigned)(nwg - 1)) {
            __hip_atomic_store(cnt, 0u, __ATOMIC_RELAXED, SCOPE_AGENT);
            __hip_atomic_fetch_add(gen, 1u, __ATOMIC_ACQ_REL, SCOPE_AGENT);
        } else {
            while (__hip_atomic_load(gen, __ATOMIC_RELAXED, SCOPE_AGENT) == g)
                __builtin_amdgcn_s_sleep(2);
        }
        __threadfence();
    }
    __syncthreads();
}

__global__ __launch_bounds__(512, 2) void fused_all(
        const int* __restrict__ x, const int* __restrict__ taskp,
        const float* __restrict__ embed,
        const float* __restrict__ Wx_t, const float* __restrict__ Wh_t,
        const float* __restrict__ b_t,
        const float* __restrict__ Ws_p1, const float* __restrict__ Ws_p2,
        const float* __restrict__ Us_w,
        const float* __restrict__ Wx_c, const float* __restrict__ Wh_c,
        const float* __restrict__ Wm_c, const float* __restrict__ b_c,
        float* __restrict__ out,
        float* __restrict__ emb, float* __restrict__ p1t,
        float* __restrict__ h_task, float* __restrict__ c_task,
        float* __restrict__ h_main, float* __restrict__ c_main,
        float* __restrict__ p2w, float* __restrict__ partial,
        unsigned* __restrict__ bar)
{
    __shared__ float sact[512 * PADA];
    __shared__ float swt[2][4096];
    __shared__ float smisc[2048];

    const int wg = blockIdx.x, tid = threadIdx.x;
    const int task = taskp[0];

    // ---------------- prologue ----------------
    for (int i = wg * 512 + tid; i < 393216; i += 131072)
        stg(&h_task[i], 0.f);  // h_task(2)+c_task+h_main(2)+c_main contiguous
    for (int w = wg * 2 + (tid >> 8); w < S_ * B_; w += 512) {
        int ts = w >> 5, b = w & 31;
        int tok = x[b * S_ + ts];
        stg(&emb[(size_t)w * E_ + (tid & 255)], embed[(size_t)tok * E_ + (tid & 255)]);
    }
    for (int i = wg * 512 + tid; i < H_ * H_; i += 131072) {
        int j = i >> 9, ii = i & 511;
        stg(&p1t[i], Ws_p1[ii * H_ + j]);
    }
    gbar(bar, tid, 256);

    for (int t = 0; t < S_; ++t) {
        const int old = t & 1, nw = old ^ 1;
        float* ht_old = h_task + (size_t)old * K_ * B_ * H_;
        float* ht_new = h_task + (size_t)nw * K_ * B_ * H_;
        float* hm_old = h_main + (size_t)old * B_ * H_;
        float* hm_new = h_main + (size_t)nw * B_ * H_;

        // ================= Phase A =================
        if (wg < 232) {
            const int cp = tid & 31, bq = tid >> 5;
            const int l0 = 2 * cp;
            const int rr = tid >> 4, cc4 = (tid & 15) << 2;
            const bool istask = wg < 224;
            int k = 0, nt = 0, pb = 0, kk = 0;
            const float* W0; const float* W1; int n0, n1; size_t ld;
            if (istask) {
                k = wg >> 5; nt = wg & 31;
                kk = k + (k >= task);
                int gcolL = ((cc4 >> 4) << 9) + nt * 16 + (cc4 & 15);
                W0 = Wx_t + (size_t)kk * E_ * G_ + gcolL;
                W1 = Wh_t + (size_t)kk * H_ * G_ + gcolL;
                n0 = 4; n1 = 8; ld = G_;
            } else {
                pb = wg - 224;
                int gcolL = pb * 64 + cc4;
                W0 = Ws_p2 + gcolL;
                W1 = Ws_p2 + (size_t)512 * H_ + gcolL;
                n0 = 8; n1 = 4; ld = H_;
            }
            float a00 = 0.f, a01 = 0.f, a10 = 0.f, a11 = 0.f;
            float4 R0, R1;
            for (int part = 0; part < 2; ++part) {
                if (istask) {
                    if (part == 0) {
                        for (int idx = tid; idx < 256 * 32; idx += 512) {
                            int r = idx & 255, b = idx >> 8;
                            sact[r * PADA + b] = emb[((size_t)t * B_ + b) * E_ + r];
                        }
                    } else {
                        for (int idx = tid; idx < 512 * 32; idx += 512) {
                            int r = idx & 511, b = idx >> 9;
                            sact[r * PADA + b] = ht_old[((size_t)k * B_ + b) * H_ + r];
                        }
                    }
                } else {
                    if (part == 0) {
                        for (int idx = tid; idx < 512 * 32; idx += 512) {
                            int r = idx & 511, b = idx >> 9;
                            sact[r * PADA + b] = hm_old[(size_t)b * H_ + r];
                        }
                    } else {
                        for (int idx = tid; idx < 256 * 32; idx += 512) {
                            int r = idx & 255, b = idx >> 8;
                            sact[r * PADA + b] = emb[((size_t)t * B_ + b) * E_ + r];
                        }
                    }
                }
                const float* W = part ? W1 : W0;
                const int NC = part ? n1 : n0;
                R0 = *(const float4*)(W + (size_t)rr * ld);
                R1 = *(const float4*)(W + (size_t)(rr + 32) * ld);
                __syncthreads();
                *(float4*)(swt[0] + rr * 64 + cc4) = R0;
                *(float4*)(swt[0] + (rr + 32) * 64 + cc4) = R1;
                if (NC > 1) {
                    R0 = *(const float4*)(W + (size_t)(64 + rr) * ld);
                    R1 = *(const float4*)(W + (size_t)(64 + rr + 32) * ld);
                }
                __syncthreads();
                int cur = 0;
                for (int ch = 0; ch < NC; ++ch) {
                    const float* wb = swt[cur] + l0;
                    const float* ab = sact + (size_t)(ch << 6) * PADA + 2 * bq;
#pragma unroll 8
                    for (int r = 0; r < 64; ++r) {
                        float2 w = *(const float2*)(wb + r * 64);
                        float2 av = *(const float2*)(ab + r * PADA);
                        a00 = fmaf(w.x, av.x, a00); a10 = fmaf(w.y, av.x, a10);
                        a01 = fmaf(w.x, av.y, a01); a11 = fmaf(w.y, av.y, a11);
                    }
                    __syncthreads();
                    if (ch + 1 < NC) {
                        *(float4*)(swt[cur ^ 1] + rr * 64 + cc4) = R0;
                        *(float4*)(swt[cur ^ 1] + (rr + 32) * 64 + cc4) = R1;
                        if (ch + 2 < NC) {
                            R0 = *(const float4*)(W + (size_t)((ch + 2) * 64 + rr) * ld);
                            R1 = *(const float4*)(W + (size_t)((ch + 2) * 64 + rr + 32) * ld);
                        }
                        __syncthreads();
                        cur ^= 1;
                    }
                }
            }
            if (istask) {
                smisc[(2 * bq) * 64 + l0]         = a00;
                smisc[(2 * bq) * 64 + l0 + 1]     = a10;
                smisc[(2 * bq + 1) * 64 + l0]     = a01;
                smisc[(2 * bq + 1) * 64 + l0 + 1] = a11;
                __syncthreads();
                int b = tid >> 4, hc = tid & 15;
                const float* bb = b_t + kk * G_ + nt * 16 + hc;
                float gi = smisc[b * 64 + hc]      + bb[0];
                float gf = smisc[b * 64 + 16 + hc] + bb[512];
                float gg = smisc[b * 64 + 32 + hc] + bb[1024];
                float go = smisc[b * 64 + 48 + hc] + bb[1536];
                size_t cidx = ((size_t)k * B_ + b) * H_ + nt * 16 + hc;
                float cold = c_task[cidx];
                float cn = sigm(gf) * cold + sigm(gi) * tanhf(gg);
                float hn = sigm(go) * tanhf(cn);
                c_task[cidx] = cn;
                stg(&ht_new[cidx], hn);
            } else {
                stg(&p2w[(size_t)(2 * bq) * H_ + pb * 64 + l0],         a00);
                stg(&p2w[(size_t)(2 * bq) * H_ + pb * 64 + l0 + 1],     a10);
                stg(&p2w[(size_t)(2 * bq + 1) * H_ + pb * 64 + l0],     a01);
                stg(&p2w[(size_t)(2 * bq + 1) * H_ + pb * 64 + l0 + 1], a11);
            }
        }
        gbar(bar, tid, 256);

        // ================= Phase B =================
        if (wg < 224) {
            const int kt = wg >> 5, it = wg & 31;
            const int ci = tid & 15, b = tid >> 4;
            for (int idx = tid; idx < 512 * 32 / 4; idx += 512) {
                int b2 = idx >> 7, j4 = (idx & 127) << 2;
                float4 v = *(const float4*)(ht_new + ((size_t)kt * B_ + b2) * H_ + j4);
                float* d = sact + b2 * PADB + j4;
                d[0] = v.x; d[1] = v.y; d[2] = v.z; d[3] = v.w;
            }
            const int rb = tid >> 3, cb = (tid & 7) << 1;
            const float* Wp = p1t + it * 16 + cb;
            float2 Rb = *(const float2*)(Wp + (size_t)rb * H_);
            __syncthreads();
            *(float2*)(swt[0] + rb * 16 + cb) = Rb;
            Rb = *(const float2*)(Wp + (size_t)(64 + rb) * H_);
            __syncthreads();
            float acc = 0.f;
            const float* hb = sact + b * PADB;
            int cur = 0;
            for (int ch = 0; ch < 8; ++ch) {
                const float* wb = swt[cur] + ci;
                const float* ab = hb + (ch << 6);
#pragma unroll 8
                for (int r = 0; r < 64; ++r)
                    acc = fmaf(wb[r * 16], ab[r], acc);
                __syncthreads();
                if (ch + 1 < 8) {
                    *(float2*)(swt[cur ^ 1] + rb * 16 + cb) = Rb;
                    if (ch + 2 < 8)
                        Rb = *(const float2*)(Wp + (size_t)((ch + 2) * 64 + rb) * H_);
                    __syncthreads();
                    cur ^= 1;
                }
            }
            int icol = it * 16 + ci;
            float s = tanhf(acc + p2w[(size_t)b * H_ + icol]) * Us_w[icol];
#pragma unroll
            for (int m = 1; m < 16; m <<= 1) s += __shfl_xor(s, m, 64);
            if (ci == 0) stg(&partial[((size_t)kt * 32 + it) * 32 + b], s);
        }
        gbar(bar, tid, 256);

        // ================= Phase C =================
        {
            const int bt = wg >> 5, nt = wg & 31;
            const int cp = tid & 31, bl = (tid >> 5) & 3, ds = tid >> 7;
            const int l0 = 2 * cp;
            const int rr = tid >> 4, cc4 = (tid & 15) << 2;
            const int gcolL = ((cc4 >> 4) << 9) + nt * 16 + (cc4 & 15);
            float* ssi = smisc;
            float* sa  = smisc + 32;
            float* sgt = smisc + 64;
            if (tid < 28) {
                int kq = tid >> 2, b2 = tid & 3;
                float ssum = 0.f;
                for (int itq = 0; itq < 32; ++itq)
                    ssum += partial[((size_t)kq * 32 + itq) * 32 + 4 * bt + b2];
                ssi[b2 * 7 + kq] = ssum;
            }
            __syncthreads();
            if (tid < 4) {
                float mx = -1e30f;
                for (int kq = 0; kq < 7; ++kq) mx = fmaxf(mx, ssi[tid * 7 + kq]);
                float den = 0.f, e[7];
                for (int kq = 0; kq < 7; ++kq) { e[kq] = expf(ssi[tid * 7 + kq] - mx); den += e[kq]; }
                float rd = 1.f / den;
                for (int kq = 0; kq < 7; ++kq) sa[tid * 7 + kq] = e[kq] * rd;
            }
            __syncthreads();
            for (int idx = tid; idx < 256 * 4; idx += 512) {
                int r = idx & 255, b2 = idx >> 8;
                sact[r * PADC + b2] = emb[((size_t)t * B_ + 4 * bt + b2) * E_ + r];
            }
            for (int idx = tid; idx < 512 * 4; idx += 512) {
                int r = idx & 511, b2 = idx >> 9;
                sact[(256 + r) * PADC + b2] = hm_old[(size_t)(4 * bt + b2) * H_ + r];
            }
            for (int idx = tid; idx < 512 * 4; idx += 512) {
                int r = idx & 511, b2 = idx >> 9;
                float v = 0.f;
#pragma unroll
                for (int kq = 0; kq < 7; ++kq)
                    v = fmaf(sa[b2 * 7 + kq], ht_new[((size_t)kq * B_ + 4 * bt + b2) * H_ + r], v);
                sact[(768 + r) * PADC + b2] = v;
            }
            float a0 = 0.f, a1 = 0.f;
            float4 R0, R1;
            auto wptr = [&](int ch) -> const float* {
                if (ch < 4)  return Wx_c + (size_t)(ch << 6) * G_ + gcolL;
                if (ch < 12) return Wh_c + (size_t)((ch - 4) << 6) * G_ + gcolL;
                return Wm_c + (size_t)((ch - 12) << 6) * G_ + gcolL;
            };
            const float* W = wptr(0);
            R0 = *(const float4*)(W + (size_t)rr * G_);
            R1 = *(const float4*)(W + (size_t)(rr + 32) * G_);
            __syncthreads();
            *(float4*)(swt[0] + rr * 64 + cc4) = R0;
            *(float4*)(swt[0] + (rr + 32) * 64 + cc4) = R1;
            W = wptr(1);
            R0 = *(const float4*)(W + (size_t)rr * G_);
            R1 = *(const float4*)(W + (size_t)(rr + 32) * G_);
            __syncthreads();
            int cur = 0;
            for (int ch = 0; ch < 20; ++ch) {
                const float* wb = swt[cur] + (ds << 4) * 64 + l0;
                const float* ab = sact + (size_t)((ch << 6) + (ds << 4)) * PADC + bl;
#pragma unroll 8
                for (int r = 0; r < 16; ++r) {
                    float2 w = *(const float2*)(wb + r * 64);
                    float av = ab[r * PADC];
                    a0 = fmaf(w.x, av, a0);
                    a1 = fmaf(w.y, av, a1);
                }
                __syncthreads();
                if (ch + 1 < 20) {
                    *(float4*)(swt[cur ^ 1] + rr * 64 + cc4) = R0;
                    *(float4*)(swt[cur ^ 1] + (rr + 32) * 64 + cc4) = R1;
                    if (ch + 2 < 20) {
                        W = wptr(ch + 2);
                        R0 = *(const float4*)(W + (size_t)rr * G_);
                        R1 = *(const float4*)(W + (size_t)(rr + 32) * G_);
                    }
                    __syncthreads();
                    cur ^= 1;
                }
            }
            sgt[ds * 256 + bl * 64 + l0]     = a0;
            sgt[ds * 256 + bl * 64 + l0 + 1] = a1;
            __syncthreads();
            if (tid < 64) {
                int b2 = tid >> 4, hc = tid & 15;
                int gb = 4 * bt + b2;
                float g4[4];
#pragma unroll
                for (int g = 0; g < 4; ++g) {
                    int colx = g * 16 + hc;
                    g4[g] = sgt[b2 * 64 + colx] + sgt[256 + b2 * 64 + colx]
                          + sgt[512 + b2 * 64 + colx] + sgt[768 + b2 * 64 + colx]
                          + b_c[g * 512 + nt * 16 + hc];
                }
                size_t cidx = (size_t)gb * H_ + nt * 16 + hc;
                float cold = c_main[cidx];
                float cn = sigm(g4[1]) * cold + sigm(g4[0]) * tanhf(g4[2]);
                float hn = sigm(g4[3]) * tanhf(cn);
                c_main[cidx] = cn;
                stg(&hm_new[cidx], hn);
                out[(size_t)gb * S_ * H_ + (size_t)t * H_ + nt * 16 + hc] = hn;
            }
        }
        gbar(bar, tid, 256);
    }

    for (int i = wg * 512 + tid; i < B_ * H_; i += 131072)
        out[(size_t)B_ * S_ * H_ + i] = h_main[i];
}

extern "C" void kernel_launch(void* const* d_in, const int* in_sizes, int n_in,
                              void* d_out, int out_size, void* d_ws, size_t ws_size,
                              hipStream_t stream) {
    const int*   x      = (const int*)d_in[0];
    const int*   taskp  = (const int*)d_in[1];
    const float* embed  = (const float*)d_in[2];
    const float* Wx_t   = (const float*)d_in[3];
    const float* Wh_t   = (const float*)d_in[4];
    const float* b_t    = (const float*)d_in[5];
    const float* Ws_p1  = (const float*)d_in[6];
    const float* Ws_p2  = (const float*)d_in[7];
    const float* Us_w   = (const float*)d_in[8];
    const float* Wx_c   = (const float*)d_in[10];
    const float* Wh_c   = (const float*)d_in[11];
    const float* Wm_c   = (const float*)d_in[12];
    const float* b_c    = (const float*)d_in[13];
    float* out = (float*)d_out;

    float* ws = (float*)d_ws;
    float* emb     = ws;                                  // S*B*E   = 4,194,304
    float* p1t     = emb     + (size_t)S_ * B_ * E_;      // H*H     =   262,144
    float* h_task  = p1t     + (size_t)H_ * H_;           // 2*K*B*H =   229,376
    float* c_task  = h_task  + 2 * (size_t)K_ * B_ * H_;  // K*B*H   =   114,688
    float* h_main  = c_task  + (size_t)K_ * B_ * H_;      // 2*B*H   =    32,768
    float* c_main  = h_main  + 2 * (size_t)B_ * H_;       // B*H     =    16,384
    float* p2      = c_main  + (size_t)B_ * H_;           // B*H     =    16,384
    float* partial = p2      + (size_t)B_ * H_;           // K*32*32 =     7,168
    unsigned* bar  = (unsigned*)(partial + 7168);         // 64 uints

    hipMemsetAsync(bar, 0, 256, stream);

    void* args[] = { (void*)&x, (void*)&taskp, (void*)&embed,
                     (void*)&Wx_t, (void*)&Wh_t, (void*)&b_t,
                     (void*)&Ws_p1, (void*)&Ws_p2, (void*)&Us_w,
                     (void*)&Wx_c, (void*)&Wh_c, (void*)&Wm_c, (void*)&b_c,
                     (void*)&out,
                     (void*)&emb, (void*)&p1t, (void*)&h_task, (void*)&c_task,
                     (void*)&h_main, (void*)&c_main, (void*)&p2, (void*)&partial,
                     (void*)&bar };
    hipLaunchCooperativeKernel((void*)fused_all, dim3(256), dim3(512), args, 0, stream);
}

// Round 9
// 44379.279 us; speedup vs baseline: 2.1658x; 1.5099x over previous
//
#include <hip/hip_runtime.h>

#define B_ 32
#define S_ 512
#define E_ 256
#define H_ 512
#define G_ 2048
#define K_ 7
#define PADA 34   // phase A transposed act row stride
#define PADB 513  // phase B row-major act stride
#define PADC 5    // phase C transposed act row stride
#define SCOPE __HIP_MEMORY_SCOPE_AGENT

__device__ __forceinline__ float sigm(float x) { return 1.f / (1.f + expf(-x)); }

// cross-WG coherent primitives: sc1 ops talk to the coherent point (L3);
// no cache invalidation needed anywhere -> weights stay in L1/L2 across steps.
__device__ __forceinline__ float ldc(const float* p) {
    return __hip_atomic_load(p, __ATOMIC_RELAXED, SCOPE);
}
__device__ __forceinline__ void ld2c(const float* p, float& a, float& b) {
    unsigned long long v =
        __hip_atomic_load((const unsigned long long*)p, __ATOMIC_RELAXED, SCOPE);
    a = __builtin_bit_cast(float, (unsigned)v);
    b = __builtin_bit_cast(float, (unsigned)(v >> 32));
}
__device__ __forceinline__ void stg(float* p, float v) {
    __hip_atomic_store(p, v, __ATOMIC_RELAXED, SCOPE);
}

// workgroup barrier that does NOT drain vmcnt (global prefetch stays in flight);
// drains LDS only so ds_writes are visible after the barrier.
#define BAR() asm volatile("s_waitcnt lgkmcnt(0)\n\ts_barrier" ::: "memory")

// 2-level monotonic grid barrier, all relaxed. Release = the full vmcnt drain
// hipcc emits for the entry __syncthreads; consumers use sc1 data loads, so no
// acquire-invalidate is needed.
__device__ __forceinline__ void gbar(unsigned* bar, int tid, int wg, unsigned n) {
    __syncthreads();   // compiler emits s_waitcnt vmcnt(0) lgkmcnt(0) here
    if (tid == 0) {
        int g = wg >> 5;                       // 8 groups x 32 WGs
        unsigned* gcnt = bar + 64 + g * 32;
        unsigned* ggen = bar + 320 + g * 32;
        unsigned old = __hip_atomic_fetch_add(gcnt, 1u, __ATOMIC_RELAXED, SCOPE);
        if (old == n * 32u - 1u) {             // last of group
            unsigned rold = __hip_atomic_fetch_add(bar, 1u, __ATOMIC_RELAXED, SCOPE);
            if (rold == n * 8u - 1u) {         // last group
                __hip_atomic_store(bar + 32, n, __ATOMIC_RELAXED, SCOPE);
            } else {
                while (__hip_atomic_load(bar + 32, __ATOMIC_RELAXED, SCOPE) < n)
                    __builtin_amdgcn_s_sleep(1);
            }
            __hip_atomic_store(ggen, n, __ATOMIC_RELAXED, SCOPE);
        } else {
            while (__hip_atomic_load(ggen, __ATOMIC_RELAXED, SCOPE) < n)
                __builtin_amdgcn_s_sleep(1);
        }
        asm volatile("" ::: "memory");
    }
    __syncthreads();
}

__global__ __launch_bounds__(512, 2) void fused_all(
        const int* __restrict__ x, const int* __restrict__ taskp,
        const float* __restrict__ embed,
        const float* __restrict__ Wx_t, const float* __restrict__ Wh_t,
        const float* __restrict__ b_t,
        const float* __restrict__ Ws_p1, const float* __restrict__ Ws_p2,
        const float* __restrict__ Us_w,
        const float* __restrict__ Wx_c, const float* __restrict__ Wh_c,
        const float* __restrict__ Wm_c, const float* __restrict__ b_c,
        float* __restrict__ out,
        float* __restrict__ emb, float* __restrict__ p1t,
        float* __restrict__ h_task, float* __restrict__ c_task,
        float* __restrict__ h_main, float* __restrict__ c_main,
        float* __restrict__ p2w, float* __restrict__ partial,
        unsigned* __restrict__ bar)
{
    __shared__ float sact[512 * PADA];
    __shared__ float swt[2][4096];
    __shared__ float smisc[2048];

    const int wg = blockIdx.x, tid = threadIdx.x;
    const int task = taskp[0];
    unsigned bn = 0;

    // ---------------- prologue ----------------
    for (int i = wg * 512 + tid; i < 393216; i += 131072)
        stg(&h_task[i], 0.f);  // h_task(2)+c_task+h_main(2)+c_main contiguous
    for (int w = wg * 2 + (tid >> 8); w < S_ * B_; w += 512) {
        int ts = w >> 5, b = w & 31;
        int tok = x[b * S_ + ts];
        stg(&emb[(size_t)w * E_ + (tid & 255)], embed[(size_t)tok * E_ + (tid & 255)]);
    }
    for (int i = wg * 512 + tid; i < H_ * H_; i += 131072) {
        int j = i >> 9, ii = i & 511;
        stg(&p1t[i], Ws_p1[ii * H_ + j]);
    }
    gbar(bar, tid, wg, ++bn);

    for (int t = 0; t < S_; ++t) {
        const int old = t & 1, nw = old ^ 1;
        float* ht_old = h_task + (size_t)old * K_ * B_ * H_;
        float* ht_new = h_task + (size_t)nw * K_ * B_ * H_;
        float* hm_old = h_main + (size_t)old * B_ * H_;
        float* hm_new = h_main + (size_t)nw * B_ * H_;

        // ================= Phase A: task gates+cell (wg<224) + p2 (224..231) =====
        if (wg < 232) {
            const int cp = tid & 31, bq = tid >> 5;
            const int l0 = 2 * cp;
            const int rr = tid >> 4, cc4 = (tid & 15) << 2;
            const bool istask = wg < 224;
            int k = 0, nt = 0, pb = 0, kk = 0;
            const float* W0; const float* W1; int n0, n1; size_t ld;
            if (istask) {
                k = wg >> 5; nt = wg & 31;
                kk = k + (k >= task);
                int gcolL = ((cc4 >> 4) << 9) + nt * 16 + (cc4 & 15);
                W0 = Wx_t + (size_t)kk * E_ * G_ + gcolL;
                W1 = Wh_t + (size_t)kk * H_ * G_ + gcolL;
                n0 = 4; n1 = 8; ld = G_;
            } else {
                pb = wg - 224;
                int gcolL = pb * 64 + cc4;
                W0 = Ws_p2 + gcolL;
                W1 = Ws_p2 + (size_t)512 * H_ + gcolL;
                n0 = 8; n1 = 4; ld = H_;
            }
            float a00 = 0.f, a01 = 0.f, a10 = 0.f, a11 = 0.f;
            float4 R0, R1;
            for (int part = 0; part < 2; ++part) {
                if (istask) {
                    if (part == 0) {
                        for (int idx = tid; idx < 8192; idx += 512) {
                            int r = idx & 255, b = idx >> 8;
                            sact[r * PADA + b] = emb[((size_t)t * B_ + b) * E_ + r];
                        }
                    } else {
                        for (int idx = tid; idx < 8192; idx += 512) {
                            int r2 = (idx & 255) << 1, b = idx >> 8;
                            float va, vb;
                            ld2c(&ht_old[((size_t)k * B_ + b) * H_ + r2], va, vb);
                            sact[r2 * PADA + b] = va;
                            sact[(r2 + 1) * PADA + b] = vb;
                        }
                    }
                } else {
                    if (part == 0) {
                        for (int idx = tid; idx < 8192; idx += 512) {
                            int r2 = (idx & 255) << 1, b = idx >> 8;
                            float va, vb;
                            ld2c(&hm_old[(size_t)b * H_ + r2], va, vb);
                            sact[r2 * PADA + b] = va;
                            sact[(r2 + 1) * PADA + b] = vb;
                        }
                    } else {
                        for (int idx = tid; idx < 8192; idx += 512) {
                            int r = idx & 255, b = idx >> 8;
                            sact[r * PADA + b] = emb[((size_t)t * B_ + b) * E_ + r];
                        }
                    }
                }
                const float* W = part ? W1 : W0;
                const int NC = part ? n1 : n0;
                R0 = *(const float4*)(W + (size_t)rr * ld);
                R1 = *(const float4*)(W + (size_t)(rr + 32) * ld);
                BAR();   // prev compute done + sact visible
                *(float4*)(swt[0] + rr * 64 + cc4) = R0;
                *(float4*)(swt[0] + (rr + 32) * 64 + cc4) = R1;
                if (NC > 1) {
                    R0 = *(const float4*)(W + (size_t)(64 + rr) * ld);
                    R1 = *(const float4*)(W + (size_t)(64 + rr + 32) * ld);
                }
                BAR();   // swt[0] visible; next loads stay in flight
                int p = 0;
                for (int ch = 0; ch < NC; ++ch) {
                    if (ch + 1 < NC) {
                        *(float4*)(swt[p ^ 1] + rr * 64 + cc4) = R0;
                        *(float4*)(swt[p ^ 1] + (rr + 32) * 64 + cc4) = R1;
                        if (ch + 2 < NC) {
                            R0 = *(const float4*)(W + (size_t)((ch + 2) * 64 + rr) * ld);
                            R1 = *(const float4*)(W + (size_t)((ch + 2) * 64 + rr + 32) * ld);
                        }
                    }
                    const float* wb = swt[p] + l0;
                    const float* ab = sact + (size_t)(ch << 6) * PADA + 2 * bq;
#pragma unroll 8
                    for (int r = 0; r < 64; ++r) {
                        float2 w = *(const float2*)(wb + r * 64);
                        float2 av = *(const float2*)(ab + r * PADA);
                        a00 = fmaf(w.x, av.x, a00); a10 = fmaf(w.y, av.x, a10);
                        a01 = fmaf(w.x, av.y, a01); a11 = fmaf(w.y, av.y, a11);
                    }
                    BAR();
                    p ^= 1;
                }
            }
            if (istask) {
                smisc[(2 * bq) * 64 + l0]         = a00;
                smisc[(2 * bq) * 64 + l0 + 1]     = a10;
                smisc[(2 * bq + 1) * 64 + l0]     = a01;
                smisc[(2 * bq + 1) * 64 + l0 + 1] = a11;
                BAR();
                int b = tid >> 4, hc = tid & 15;
                const float* bb = b_t + kk * G_ + nt * 16 + hc;
                float gi = smisc[b * 64 + hc]      + bb[0];
                float gf = smisc[b * 64 + 16 + hc] + bb[512];
                float gg = smisc[b * 64 + 32 + hc] + bb[1024];
                float go = smisc[b * 64 + 48 + hc] + bb[1536];
                size_t cidx = ((size_t)k * B_ + b) * H_ + nt * 16 + hc;
                float cold = c_task[cidx];                 // WG-private
                float cn = sigm(gf) * cold + sigm(gi) * tanhf(gg);
                float hn = sigm(go) * tanhf(cn);
                c_task[cidx] = cn;
                stg(&ht_new[cidx], hn);
            } else {
                stg(&p2w[(size_t)(2 * bq) * H_ + pb * 64 + l0],         a00);
                stg(&p2w[(size_t)(2 * bq) * H_ + pb * 64 + l0 + 1],     a10);
                stg(&p2w[(size_t)(2 * bq + 1) * H_ + pb * 64 + l0],     a01);
                stg(&p2w[(size_t)(2 * bq + 1) * H_ + pb * 64 + l0 + 1], a11);
            }
        }
        gbar(bar, tid, wg, ++bn);

        // ================= Phase B: attention partials (wg<224) =================
        if (wg < 224) {
            const int kt = wg >> 5, it = wg & 31;
            const int ci = tid & 15, b = tid >> 4;
            for (int idx = tid; idx < 8192; idx += 512) {
                int b2 = idx >> 8, j2 = (idx & 255) << 1;
                float va, vb;
                ld2c(&ht_new[((size_t)kt * B_ + b2) * H_ + j2], va, vb);
                sact[b2 * PADB + j2] = va;
                sact[b2 * PADB + j2 + 1] = vb;
            }
            const int rb = tid >> 3, cb = (tid & 7) << 1;
            const float* Wp = p1t + it * 16 + cb;
            float2 Rb = *(const float2*)(Wp + (size_t)rb * H_);
            BAR();
            *(float2*)(swt[0] + rb * 16 + cb) = Rb;
            Rb = *(const float2*)(Wp + (size_t)(64 + rb) * H_);
            BAR();
            float acc = 0.f;
            const float* hb = sact + b * PADB;
            int p = 0;
            for (int ch = 0; ch < 8; ++ch) {
                if (ch + 1 < 8) {
                    *(float2*)(swt[p ^ 1] + rb * 16 + cb) = Rb;
                    if (ch + 2 < 8)
                        Rb = *(const float2*)(Wp + (size_t)((ch + 2) * 64 + rb) * H_);
                }
                const float* wb2 = swt[p] + ci;
                const float* ab = hb + (ch << 6);
#pragma unroll 8
                for (int r = 0; r < 64; ++r)
                    acc = fmaf(wb2[r * 16], ab[r], acc);
                BAR();
                p ^= 1;
            }
            int icol = it * 16 + ci;
            float s = tanhf(acc + ldc(&p2w[(size_t)b * H_ + icol])) * Us_w[icol];
#pragma unroll
            for (int m = 1; m < 16; m <<= 1) s += __shfl_xor(s, m, 64);
            if (ci == 0) stg(&partial[((size_t)kt * 32 + it) * 32 + b], s);
        }
        gbar(bar, tid, wg, ++bn);

        // ================= Phase C: softmax + Rt + main gates + cell ============
        {
            const int bt = wg >> 5, nt = wg & 31;
            const int cp = tid & 31, bl = (tid >> 5) & 3, ds = tid >> 7;
            const int l0 = 2 * cp;
            const int rr = tid >> 4, cc4 = (tid & 15) << 2;
            const int gcolL = ((cc4 >> 4) << 9) + nt * 16 + (cc4 & 15);
            float* ssi = smisc;
            float* sa  = smisc + 32;
            float* sgt = smisc + 64;
            if (tid < 28) {
                int kq = tid >> 2, b2 = tid & 3;
                float ssum = 0.f;
                for (int itq = 0; itq < 32; ++itq)
                    ssum += ldc(&partial[((size_t)kq * 32 + itq) * 32 + 4 * bt + b2]);
                ssi[b2 * 7 + kq] = ssum;
            }
            BAR();
            if (tid < 4) {
                float mx = -1e30f;
                for (int kq = 0; kq < 7; ++kq) mx = fmaxf(mx, ssi[tid * 7 + kq]);
                float den = 0.f, e[7];
                for (int kq = 0; kq < 7; ++kq) { e[kq] = expf(ssi[tid * 7 + kq] - mx); den += e[kq]; }
                float rd = 1.f / den;
                for (int kq = 0; kq < 7; ++kq) sa[tid * 7 + kq] = e[kq] * rd;
            }
            for (int idx = tid; idx < 1024; idx += 512) {
                int r = idx & 255, b2 = idx >> 8;
                sact[r * PADC + b2] = emb[((size_t)t * B_ + 4 * bt + b2) * E_ + r];
            }
            for (int idx = tid; idx < 1024; idx += 512) {
                int r2 = (idx & 255) << 1, b2 = idx >> 8;
                float va, vb;
                ld2c(&hm_old[(size_t)(4 * bt + b2) * H_ + r2], va, vb);
                sact[(256 + r2) * PADC + b2] = va;
                sact[(256 + r2 + 1) * PADC + b2] = vb;
            }
            BAR();   // publish sa
            for (int idx = tid; idx < 1024; idx += 512) {
                int r2 = (idx & 255) << 1, b2 = idx >> 8;
                float v0 = 0.f, v1 = 0.f;
#pragma unroll
                for (int kq = 0; kq < 7; ++kq) {
                    float ha, hb2;
                    ld2c(&ht_new[((size_t)kq * B_ + 4 * bt + b2) * H_ + r2], ha, hb2);
                    float aq = sa[b2 * 7 + kq];
                    v0 = fmaf(aq, ha, v0);
                    v1 = fmaf(aq, hb2, v1);
                }
                sact[(768 + r2) * PADC + b2] = v0;
                sact[(768 + r2 + 1) * PADC + b2] = v1;
            }
            float a0 = 0.f, a1 = 0.f;
            float4 R0, R1;
            auto wptr = [&](int ch) -> const float* {
                if (ch < 4)  return Wx_c + (size_t)(ch << 6) * G_ + gcolL;
                if (ch < 12) return Wh_c + (size_t)((ch - 4) << 6) * G_ + gcolL;
                return Wm_c + (size_t)((ch - 12) << 6) * G_ + gcolL;
            };
            const float* W = wptr(0);
            R0 = *(const float4*)(W + (size_t)rr * G_);
            R1 = *(const float4*)(W + (size_t)(rr + 32) * G_);
            BAR();   // Rt staging visible
            *(float4*)(swt[0] + rr * 64 + cc4) = R0;
            *(float4*)(swt[0] + (rr + 32) * 64 + cc4) = R1;
            W = wptr(1);
            R0 = *(const float4*)(W + (size_t)rr * G_);
            R1 = *(const float4*)(W + (size_t)(rr + 32) * G_);
            BAR();
            int p = 0;
            for (int ch = 0; ch < 20; ++ch) {
                if (ch + 1 < 20) {
                    *(float4*)(swt[p ^ 1] + rr * 64 + cc4) = R0;
                    *(float4*)(swt[p ^ 1] + (rr + 32) * 64 + cc4) = R1;
                    if (ch + 2 < 20) {
                        W = wptr(ch + 2);
                        R0 = *(const float4*)(W + (size_t)rr * G_);
                        R1 = *(const float4*)(W + (size_t)(rr + 32) * G_);
                    }
                }
                const float* wb = swt[p] + (ds << 4) * 64 + l0;
                const float* ab = sact + (size_t)((ch << 6) + (ds << 4)) * PADC + bl;
#pragma unroll 8
                for (int r = 0; r < 16; ++r) {
                    float2 w = *(const float2*)(wb + r * 64);
                    float av = ab[r * PADC];
                    a0 = fmaf(w.x, av, a0);
                    a1 = fmaf(w.y, av, a1);
                }
                BAR();
                p ^= 1;
            }
            sgt[ds * 256 + bl * 64 + l0]     = a0;
            sgt[ds * 256 + bl * 64 + l0 + 1] = a1;
            BAR();
            if (tid < 64) {
                int b2 = tid >> 4, hc = tid & 15;
                int gb = 4 * bt + b2;
                float g4[4];
#pragma unroll
                for (int g = 0; g < 4; ++g) {
                    int colx = g * 16 + hc;
                    g4[g] = sgt[b2 * 64 + colx] + sgt[256 + b2 * 64 + colx]
                          + sgt[512 + b2 * 64 + colx] + sgt[768 + b2 * 64 + colx]
                          + b_c[g * 512 + nt * 16 + hc];
                }
                size_t cidx = (size_t)gb * H_ + nt * 16 + hc;
                float cold = c_main[cidx];                 // WG-private
                float cn = sigm(g4[1]) * cold + sigm(g4[0]) * tanhf(g4[2]);
                float hn = sigm(g4[3]) * tanhf(cn);
                c_main[cidx] = cn;
                stg(&hm_new[cidx], hn);
                out[(size_t)gb * S_ * H_ + (size_t)t * H_ + nt * 16 + hc] = hn;
            }
        }
        gbar(bar, tid, wg, ++bn);
    }

    for (int i = wg * 512 + tid; i < B_ * H_; i += 131072)
        out[(size_t)B_ * S_ * H_ + i] = ldc(&h_main[i]);
}

extern "C" void kernel_launch(void* const* d_in, const int* in_sizes, int n_in,
                              void* d_out, int out_size, void* d_ws, size_t ws_size,
                              hipStream_t stream) {
    const int*   x      = (const int*)d_in[0];
    const int*   taskp  = (const int*)d_in[1];
    const float* embed  = (const float*)d_in[2];
    const float* Wx_t   = (const float*)d_in[3];
    const float* Wh_t   = (const float*)d_in[4];
    const float* b_t    = (const float*)d_in[5];
    const float* Ws_p1  = (const float*)d_in[6];
    const float* Ws_p2  = (const float*)d_in[7];
    const float* Us_w   = (const float*)d_in[8];
    const float* Wx_c   = (const float*)d_in[10];
    const float* Wh_c   = (const float*)d_in[11];
    const float* Wm_c   = (const float*)d_in[12];
    const float* b_c    = (const float*)d_in[13];
    float* out = (float*)d_out;

    float* ws = (float*)d_ws;
    float* emb     = ws;                                  // S*B*E   = 4,194,304
    float* p1t     = emb     + (size_t)S_ * B_ * E_;      // H*H     =   262,144
    float* h_task  = p1t     + (size_t)H_ * H_;           // 2*K*B*H =   229,376
    float* c_task  = h_task  + 2 * (size_t)K_ * B_ * H_;  // K*B*H   =   114,688
    float* h_main  = c_task  + (size_t)K_ * B_ * H_;      // 2*B*H   =    32,768
    float* c_main  = h_main  + 2 * (size_t)B_ * H_;       // B*H     =    16,384
    float* p2      = c_main  + (size_t)B_ * H_;           // B*H     =    16,384
    float* partial = p2      + (size_t)B_ * H_;           // K*32*32 =     7,168
    unsigned* bar  = (unsigned*)(partial + 7168);         // 576 uints (2-level barrier)

    hipMemsetAsync(bar, 0, 4096, stream);

    void* args[] = { (void*)&x, (void*)&taskp, (void*)&embed,
                     (void*)&Wx_t, (void*)&Wh_t, (void*)&b_t,
                     (void*)&Ws_p1, (void*)&Ws_p2, (void*)&Us_w,
                     (void*)&Wx_c, (void*)&Wh_c, (void*)&Wm_c, (void*)&b_c,
                     (void*)&out,
                     (void*)&emb, (void*)&p1t, (void*)&h_task, (void*)&c_task,
                     (void*)&h_main, (void*)&c_main, (void*)&p2, (void*)&partial,
                     (void*)&bar };
    hipLaunchCooperativeKernel((void*)fused_all, dim3(256), dim3(512), args, 0, stream);
}